// Round 6
// baseline (130.369 us; speedup 1.0000x reference)
//
#include <hip/hip_runtime.h>

// Per-sample 3x3 conv as bf16 implicit GEMM, NHWC, SAME padding.
// x: (32,128,128,32) f32; params: (32, 9216+32) f32; out: (32,128,128,32) f32
// Per sample: GEMM M=16384 px, N=32 f, K=288=(kh,kw,ci).
//
// R5 changes vs R4:
//  - SWAPPED MFMA operands: mfma(W_frag, X_frag) -> D^T. Fragments are
//    identical (A/B lane maps symmetric); C layout now lane: px=li,
//    f=lg*4+reg -> epilogue is 8 dwordx4 stores (was 32 scalar dword).
//  - bf16 pack via round-half-up + v_perm_b32 (3 VALU per 2 floats,
//    was ~10 with RNE tie handling).
//  - Staging loads fully issued into regs before conversion (max MLP);
//    first W-fragments issued pre-barrier.

typedef __attribute__((ext_vector_type(8))) short bf16x8;
typedef __attribute__((ext_vector_type(4))) float f32x4;

constexpr int HWD  = 128, CINC = 32, FC = 32;
constexpr int WSZ  = 9 * CINC * FC;         // 9216
constexpr int PSTR = WSZ + FC;              // 9248

// xs[cig=4][row=4][col=130][8ci as 16B], +32B pad per cig plane
constexpr int XS_PLANE  = 4 * 130 * 16;            // 8320
constexpr int XS_BYTES  = 4 * (XS_PLANE + 32);     // 33408
// fallback weight region (appended): wt[kgrp=36][f=32][8k as 16B]
constexpr int WT_BYTES  = 36 * 32 * 16;            // 18432

constexpr size_t WS_FRAGS = 32ull * 36 * 32;       // bf16x8 frags in workspace
constexpr size_t WS_NEED  = WS_FRAGS * 16;         // 589,824 B

__device__ __forceinline__ int xs_off(int cig, int r, int col) {
    return ((cig * 4 + r) * 130 + col) * 16 + cig * 32;
}
__device__ __forceinline__ int wt_off(int kgrp, int f) {
    return XS_BYTES + (kgrp * 32 + f) * 16;
}

// exact RNE (used in prep kernel only; off critical path)
__device__ __forceinline__ unsigned short f2bf(float f) {
    unsigned u = __float_as_uint(f);
    return (unsigned short)((u + 0x7FFFu + ((u >> 16) & 1u)) >> 16);
}
__device__ __forceinline__ bf16x8 pack8(float4 a, float4 b) {
    bf16x8 r;
    r[0] = (short)f2bf(a.x); r[1] = (short)f2bf(a.y);
    r[2] = (short)f2bf(a.z); r[3] = (short)f2bf(a.w);
    r[4] = (short)f2bf(b.x); r[5] = (short)f2bf(b.y);
    r[6] = (short)f2bf(b.z); r[7] = (short)f2bf(b.w);
    return r;
}

// fast pack: round-half-up + v_perm_b32 (two floats -> packed 2xbf16)
__device__ __forceinline__ unsigned pk2(float lo, float hi) {
    const unsigned a = __float_as_uint(lo) + 0x8000u;
    const unsigned b = __float_as_uint(hi) + 0x8000u;
    // out bytes: [a.b2, a.b3, b.b2, b.b3]  (sel 0..3 -> src1, 4..7 -> src0)
    return __builtin_amdgcn_perm(b, a, 0x07060302u);
}
__device__ __forceinline__ bf16x8 pack8f(float4 a, float4 b) {
    union { int4 i; bf16x8 h; } u;
    u.i.x = (int)pk2(a.x, a.y);
    u.i.y = (int)pk2(a.z, a.w);
    u.i.z = (int)pk2(b.x, b.y);
    u.i.w = (int)pk2(b.z, b.w);
    return u.h;
}

// ---------------- prep: per-sample W fp32 -> bf16 fragment layout ----------
// ws[b*1152 + sg*32 + f] (bf16x8) = W[k = sg*8 .. sg*8+7][f],  sg = 0..35
__global__ __launch_bounds__(256) void wprep(
    const float* __restrict__ params, bf16x8* __restrict__ ws)
{
    const int b   = blockIdx.y;      // 0..31
    const int seg = blockIdx.x;      // 0..3 (288 items each)
    const float* __restrict__ pw = params + (size_t)b * PSTR;
    #pragma unroll
    for (int i = 0; i < 2; ++i) {
        const int idx = threadIdx.x + i * 256;
        if (idx < 288) {
            const int c  = seg * 288 + idx;     // 0..1151
            const int sg = c >> 5;
            const int f  = c & 31;
            const float* p = pw + (size_t)(sg * 8) * FC + f;
            float4 a, bb;
            a.x  = p[0 * FC]; a.y  = p[1 * FC]; a.z  = p[2 * FC]; a.w  = p[3 * FC];
            bb.x = p[4 * FC]; bb.y = p[5 * FC]; bb.z = p[6 * FC]; bb.w = p[7 * FC];
            ws[(size_t)b * 1152 + c] = pack8(a, bb);
        }
    }
}

// ---------------- main ----------------
template<bool USE_WS>
__global__ __launch_bounds__(256, USE_WS ? 4 : 3) void conv3x3_mfma(
    const float* __restrict__ x, const float* __restrict__ params,
    float* __restrict__ out, const bf16x8* __restrict__ ws)
{
    __shared__ __align__(16) unsigned char smem[XS_BYTES + (USE_WS ? 0 : WT_BYTES)];

    // XCD-bijective swizzle (2048 % 8 == 0): same-sample blocks share an XCD.
    const int hw      = blockIdx.x;
    const int logical = (hw & 7) * 256 + (hw >> 3);
    const int b       = logical >> 6;
    const int y0      = (logical & 63) * 2;

    const int t = threadIdx.x;
    const float* __restrict__ xb = x + (size_t)b * (HWD * HWD * CINC);
    const float* __restrict__ pw = params + (size_t)b * PSTR;

    const int wv   = t >> 6;
    const int ln   = t & 63;
    const int lg   = ln >> 4;         // k-group (also cig for A-frag)
    const int li   = ln & 15;         // px-in-tile (after swap)
    const int yloc = wv >> 1;
    const int xw   = (wv & 1) * 64;

    const size_t wsb = (size_t)b * 1152 + lg * 32;   // bf16x8 units

    // ---- phase 1: issue ALL staging loads into registers (max in-flight)
    // item c = ((r*130 + col)*4 + cig); r=lds row, col includes L/R pad.
    float4 xr[9][2];
    bool   inr[9];
    #pragma unroll
    for (int i = 0; i < 9; ++i) {
        const int c = t + i * 256;
        const int cig      = c & 3;
        const unsigned q   = (unsigned)(c >> 2);     // 0..519
        const unsigned r   = q / 130u;
        const unsigned col = q - r * 130u;
        const int iy   = y0 - 1 + (int)r;
        const int icol = (int)col - 1;
        inr[i] = (c < 2080) && ((unsigned)iy < 128u) && ((unsigned)icol < 128u);
        if (inr[i]) {
            const float* p = xb + ((size_t)iy * HWD + icol) * CINC + cig * 8;
            xr[i][0] = *(const float4*)(p);
            xr[i][1] = *(const float4*)(p + 4);
        }
    }

    // issue first W-fragments early (L2 latency overlaps conversion+barrier)
    bf16x8 bc0, bc1;
    if constexpr (USE_WS) {
        bc0 = ws[wsb + li];
        bc1 = ws[wsb + 16 + li];
    }

    // ---- phase 2: convert + LDS write
    #pragma unroll
    for (int i = 0; i < 9; ++i) {
        const int c = t + i * 256;
        if (c < 2080) {
            const int cig      = c & 3;
            const unsigned q   = (unsigned)(c >> 2);
            const unsigned r   = q / 130u;
            const unsigned col = q - r * 130u;
            bf16x8 v = 0;
            if (inr[i]) v = pack8f(xr[i][0], xr[i][1]);
            *(bf16x8*)(smem + xs_off(cig, (int)r, (int)col)) = v;
        }
    }

    if constexpr (!USE_WS) {
        // fallback: stage W^T into LDS
        #pragma unroll
        for (int j = 0; j < 5; ++j) {
            const int c    = t + j * 256;
            const int kgrp = c >> 5;
            const int f    = c & 31;
            if (kgrp < 36) {
                const float* p = pw + (size_t)(kgrp * 8) * FC + f;
                float4 a, bb;
                a.x  = p[0 * FC]; a.y  = p[1 * FC]; a.z  = p[2 * FC]; a.w  = p[3 * FC];
                bb.x = p[4 * FC]; bb.y = p[5 * FC]; bb.z = p[6 * FC]; bb.w = p[7 * FC];
                *(bf16x8*)(smem + wt_off(kgrp, f)) = pack8(a, bb);
            }
        }
    }
    __syncthreads();

    // ---- main loop: wave -> 64 px (4 M-tiles) x 32 f (2 N-tiles), SWAPPED:
    // acc = mfma(W_frag, X_frag): lane holds D^T[f = lg*4+reg + n*16][px = li]
    f32x4 acc[4][2];
    #pragma unroll
    for (int i = 0; i < 4; ++i) { acc[i][0] = (f32x4)0.0f; acc[i][1] = (f32x4)0.0f; }

    #pragma unroll
    for (int s = 0; s < 9; ++s) {
        const int kh = s / 3, kw = s % 3;
        bf16x8 b0, b1, bn0, bn1;
        if constexpr (USE_WS) {
            if (s < 8) {                      // double-buffer next tap
                bn0 = ws[wsb + (s + 1) * 128 + li];
                bn1 = ws[wsb + (s + 1) * 128 + 16 + li];
            }
            b0 = bc0; b1 = bc1;
        } else {
            b0 = *(const bf16x8*)(smem + wt_off(s * 4 + lg, li));
            b1 = *(const bf16x8*)(smem + wt_off(s * 4 + lg, 16 + li));
        }
        const int r = yloc + kh;
        const int colbase = xw + li + kw;
        #pragma unroll
        for (int tI = 0; tI < 4; ++tI) {
            const bf16x8 a = *(const bf16x8*)(smem + xs_off(lg, r, colbase + tI * 16));
            acc[tI][0] = __builtin_amdgcn_mfma_f32_16x16x32_bf16(b0, a, acc[tI][0], 0, 0, 0);
            acc[tI][1] = __builtin_amdgcn_mfma_f32_16x16x32_bf16(b1, a, acc[tI][1], 0, 0, 0);
        }
        if constexpr (USE_WS) { bc0 = bn0; bc1 = bn1; }
    }

    // ---- epilogue: lane holds f = n*16 + lg*4 + reg, px = xw + tI*16 + li
    // -> one float4 store per (tI, n)
    const float4 bias0 = *(const float4*)(pw + WSZ + lg * 4);
    const float4 bias1 = *(const float4*)(pw + WSZ + 16 + lg * 4);
    const int yo = y0 + yloc;
    float* __restrict__ ob = out + ((size_t)(b * HWD + yo)) * (HWD * FC);

    #pragma unroll
    for (int tI = 0; tI < 4; ++tI) {
        const int px = xw + tI * 16 + li;
        float* q = ob + (size_t)px * FC + lg * 4;
        float4 v0, v1;
        v0.x = acc[tI][0][0] + bias0.x; v0.y = acc[tI][0][1] + bias0.y;
        v0.z = acc[tI][0][2] + bias0.z; v0.w = acc[tI][0][3] + bias0.w;
        v1.x = acc[tI][1][0] + bias1.x; v1.y = acc[tI][1][1] + bias1.y;
        v1.z = acc[tI][1][2] + bias1.z; v1.w = acc[tI][1][3] + bias1.w;
        *(float4*)(q)      = v0;
        *(float4*)(q + 16) = v1;
    }
}

extern "C" void kernel_launch(void* const* d_in, const int* in_sizes, int n_in,
                              void* d_out, int out_size, void* d_ws, size_t ws_size,
                              hipStream_t stream)
{
    const float* x      = (const float*)d_in[0];
    const float* params = (const float*)d_in[1];
    float*       out    = (float*)d_out;

    if (ws_size >= WS_NEED && d_ws != nullptr) {
        bf16x8* ws = (bf16x8*)d_ws;
        hipLaunchKernelGGL(wprep, dim3(4, 32), dim3(256), 0, stream, params, ws);
        hipLaunchKernelGGL((conv3x3_mfma<true>), dim3(2048), dim3(256), 0, stream,
                           x, params, out, (const bf16x8*)ws);
    } else {
        hipLaunchKernelGGL((conv3x3_mfma<false>), dim3(2048), dim3(256), 0, stream,
                           x, params, out, (const bf16x8*)nullptr);
    }
}

// Round 8
// 130.283 us; speedup vs baseline: 1.0007x; 1.0007x over previous
//
#include <hip/hip_runtime.h>

// Per-sample 3x3 conv as bf16 implicit GEMM, NHWC, SAME padding.
// x: (32,128,128,32) f32; params: (32, 9216+32) f32; out: (32,128,128,32) f32
// Per sample: GEMM M=16384 px, N=32 f, K=288=(kh,kw,ci).
//
// R7 changes vs R6 (anti-convoy software pipeline):
//  - Grid 512 persistent blocks; each block processes 4 row-pair tiles of one
//    sample with DOUBLE-BUFFERED LDS x-tile (2 x 33.4 KB). Per tile:
//    convert+ds_write(buf) -> barrier -> issue NEXT tile's global loads into
//    regs -> compute(buf)+store. Staging latency hides under previous tile's
//    MFMA/epilogue; HBM demand becomes continuous (was: all blocks staged in
//    lock-step, fetch and compute never overlapped).
//  - Staging address math (div 130 etc.) hoisted out of the tile loop.
//  - One barrier per tile (write(t+2) ordered after reads of compute(t) by
//    barrier(t+1)).
// Kept from R5/R6: swapped mfma(W,X) -> dwordx4 epilogue stores; v_perm bf16
// pack; W prep kernel into d_ws (bf16 fragment layout, L2-resident).

typedef __attribute__((ext_vector_type(8))) short bf16x8;
typedef __attribute__((ext_vector_type(4))) float f32x4;

constexpr int HWD  = 128, CINC = 32, FC = 32;
constexpr int WSZ  = 9 * CINC * FC;         // 9216
constexpr int PSTR = WSZ + FC;              // 9248

// xs[cig=4][row=4][col=130][8ci as 16B], +32B pad per cig plane
constexpr int XS_PLANE  = 4 * 130 * 16;            // 8320
constexpr int XS_BYTES  = 4 * (XS_PLANE + 32);     // 33408 per buffer
// fallback weight region (appended): wt[kgrp=36][f=32][8k as 16B]
constexpr int WT_BYTES  = 36 * 32 * 16;            // 18432

constexpr size_t WS_FRAGS = 32ull * 36 * 32;       // bf16x8 frags in workspace
constexpr size_t WS_NEED  = WS_FRAGS * 16;         // 589,824 B

__device__ __forceinline__ int xs_off(int cig, int r, int col) {
    return ((cig * 4 + r) * 130 + col) * 16 + cig * 32;
}
__device__ __forceinline__ int wt_off(int kgrp, int f) {
    return 2 * XS_BYTES + (kgrp * 32 + f) * 16;
}

// exact RNE (prep kernel only)
__device__ __forceinline__ unsigned short f2bf(float f) {
    unsigned u = __float_as_uint(f);
    return (unsigned short)((u + 0x7FFFu + ((u >> 16) & 1u)) >> 16);
}
__device__ __forceinline__ bf16x8 pack8(float4 a, float4 b) {
    bf16x8 r;
    r[0] = (short)f2bf(a.x); r[1] = (short)f2bf(a.y);
    r[2] = (short)f2bf(a.z); r[3] = (short)f2bf(a.w);
    r[4] = (short)f2bf(b.x); r[5] = (short)f2bf(b.y);
    r[6] = (short)f2bf(b.z); r[7] = (short)f2bf(b.w);
    return r;
}

// fast pack: round-half-up + v_perm_b32
__device__ __forceinline__ unsigned pk2(float lo, float hi) {
    const unsigned a = __float_as_uint(lo) + 0x8000u;
    const unsigned b = __float_as_uint(hi) + 0x8000u;
    return __builtin_amdgcn_perm(b, a, 0x07060302u);
}
__device__ __forceinline__ bf16x8 pack8f(float4 a, float4 b) {
    union { int4 i; bf16x8 h; } u;
    u.i.x = (int)pk2(a.x, a.y);
    u.i.y = (int)pk2(a.z, a.w);
    u.i.z = (int)pk2(b.x, b.y);
    u.i.w = (int)pk2(b.z, b.w);
    return u.h;
}

// ---------------- prep: per-sample W fp32 -> bf16 fragment layout ----------
__global__ __launch_bounds__(256) void wprep(
    const float* __restrict__ params, bf16x8* __restrict__ ws)
{
    const int b   = blockIdx.y;
    const int seg = blockIdx.x;      // 0..3
    const float* __restrict__ pw = params + (size_t)b * PSTR;
    #pragma unroll
    for (int i = 0; i < 2; ++i) {
        const int idx = threadIdx.x + i * 256;
        if (idx < 288) {
            const int c  = seg * 288 + idx;
            const int sg = c >> 5;
            const int f  = c & 31;
            const float* p = pw + (size_t)(sg * 8) * FC + f;
            float4 a, bb;
            a.x  = p[0 * FC]; a.y  = p[1 * FC]; a.z  = p[2 * FC]; a.w  = p[3 * FC];
            bb.x = p[4 * FC]; bb.y = p[5 * FC]; bb.z = p[6 * FC]; bb.w = p[7 * FC];
            ws[(size_t)b * 1152 + c] = pack8(a, bb);
        }
    }
}

// ---------------- main ----------------
template<bool USE_WS>
__global__ __launch_bounds__(256, 2) void conv3x3_mfma(
    const float* __restrict__ x, const float* __restrict__ params,
    float* __restrict__ out, const bf16x8* __restrict__ ws)
{
    __shared__ __align__(16) unsigned char smem[2 * XS_BYTES + (USE_WS ? 0 : WT_BYTES)];

    // 512 blocks; XCD-bijective swizzle (512 % 8 == 0). 16 blocks/sample.
    const int hw  = blockIdx.x;
    const int swz = (hw & 7) * 64 + (hw >> 3);
    const int b   = swz >> 4;         // sample 0..31
    const int qrp = swz & 15;         // base row-pair; tiles: qrp + tt*16

    const int t = threadIdx.x;
    const float* __restrict__ xb = x + (size_t)b * (HWD * HWD * CINC);
    const float* __restrict__ pw = params + (size_t)b * PSTR;

    const int wv   = t >> 6;
    const int ln   = t & 63;
    const int lg   = ln >> 4;         // k-group (cig)
    const int li   = ln & 15;         // px-in-tile (swapped C layout)
    const int yloc = wv >> 1;
    const int xw   = (wv & 1) * 64;

    const size_t wsb = (size_t)b * 1152 + lg * 32;   // bf16x8 units

    // ---- per-thread staging constants (hoisted out of tile loop)
    int  r_i[9], ldsoff_i[9], xoff_i[9];
    bool colok_i[9];
    #pragma unroll
    for (int i = 0; i < 9; ++i) {
        const int c = t + i * 256;               // 0..2303; valid < 2080
        const int cig      = c & 3;
        const unsigned q2  = (unsigned)(c >> 2); // 0..575
        const unsigned r   = q2 / 130u;
        const unsigned col = q2 - r * 130u;
        const int icol = (int)col - 1;
        r_i[i]      = (int)r;
        colok_i[i]  = (c < 2080) && ((unsigned)icol < 128u);
        ldsoff_i[i] = xs_off(cig, (int)r, (int)col);
        xoff_i[i]   = icol * CINC + cig * 8;
    }

    float4 xr[9][2];
    bool   inr[9];

    auto stage_issue = [&](int y0t) {
        #pragma unroll
        for (int i = 0; i < 9; ++i) {
            const int iy = y0t - 1 + r_i[i];
            inr[i] = colok_i[i] && ((unsigned)iy < 128u);
            if (inr[i]) {
                const float* p = xb + (size_t)iy * (HWD * CINC) + xoff_i[i];
                xr[i][0] = *(const float4*)(p);
                xr[i][1] = *(const float4*)(p + 4);
            }
        }
    };

    if constexpr (!USE_WS) {
        // fallback: stage W^T into LDS once per block
        #pragma unroll
        for (int j = 0; j < 5; ++j) {
            const int c    = t + j * 256;
            const int kgrp = c >> 5;
            const int f    = c & 31;
            if (kgrp < 36) {
                const float* p = pw + (size_t)(kgrp * 8) * FC + f;
                float4 a, bb;
                a.x  = p[0 * FC]; a.y  = p[1 * FC]; a.z  = p[2 * FC]; a.w  = p[3 * FC];
                bb.x = p[4 * FC]; bb.y = p[5 * FC]; bb.z = p[6 * FC]; bb.w = p[7 * FC];
                *(bf16x8*)(smem + wt_off(kgrp, f)) = pack8(a, bb);
            }
        }
    }

    // bias (same for all tiles)
    const float4 bias0 = *(const float4*)(pw + WSZ + lg * 4);
    const float4 bias1 = *(const float4*)(pw + WSZ + 16 + lg * 4);

    // ---- pipelined tile loop: 4 row-pair tiles per block
    stage_issue(qrp * 2);
    for (int tt = 0; tt < 4; ++tt) {
        const int y0t = (qrp + tt * 16) * 2;
        unsigned char* __restrict__ sb = smem + (tt & 1) * XS_BYTES;

        // convert + LDS write for this tile
        #pragma unroll
        for (int i = 0; i < 9; ++i) {
            if (t + i * 256 < 2080) {
                bf16x8 v = 0;
                if (inr[i]) v = pack8f(xr[i][0], xr[i][1]);
                *(bf16x8*)(sb + ldsoff_i[i]) = v;
            }
        }
        __syncthreads();

        // issue next tile's global loads (hide HBM latency under compute)
        if (tt < 3) stage_issue((qrp + (tt + 1) * 16) * 2);

        // compute from sb: acc = mfma(W_frag, X_frag) -> D^T
        f32x4 acc[4][2];
        #pragma unroll
        for (int i = 0; i < 4; ++i) { acc[i][0] = (f32x4)0.0f; acc[i][1] = (f32x4)0.0f; }

        bf16x8 bc0, bc1;
        if constexpr (USE_WS) {
            bc0 = ws[wsb + li];
            bc1 = ws[wsb + 16 + li];
        }

        #pragma unroll
        for (int s = 0; s < 9; ++s) {
            const int kh = s / 3, kw = s % 3;
            bf16x8 b0, b1, bn0, bn1;
            if constexpr (USE_WS) {
                if (s < 8) {                      // double-buffer next tap
                    bn0 = ws[wsb + (s + 1) * 128 + li];
                    bn1 = ws[wsb + (s + 1) * 128 + 16 + li];
                }
                b0 = bc0; b1 = bc1;
            } else {
                b0 = *(const bf16x8*)(smem + wt_off(s * 4 + lg, li));
                b1 = *(const bf16x8*)(smem + wt_off(s * 4 + lg, 16 + li));
            }
            const int r = yloc + kh;
            const int colbase = xw + li + kw;
            #pragma unroll
            for (int tI = 0; tI < 4; ++tI) {
                const bf16x8 a = *(const bf16x8*)(sb + xs_off(lg, r, colbase + tI * 16));
                acc[tI][0] = __builtin_amdgcn_mfma_f32_16x16x32_bf16(b0, a, acc[tI][0], 0, 0, 0);
                acc[tI][1] = __builtin_amdgcn_mfma_f32_16x16x32_bf16(b1, a, acc[tI][1], 0, 0, 0);
            }
            if constexpr (USE_WS) { bc0 = bn0; bc1 = bn1; }
        }

        // epilogue: lane holds f = n*16 + lg*4 + reg, px = xw + tI*16 + li
        const int yo = y0t + yloc;
        float* __restrict__ ob = out + ((size_t)(b * HWD + yo)) * (HWD * FC);
        #pragma unroll
        for (int tI = 0; tI < 4; ++tI) {
            const int px = xw + tI * 16 + li;
            float* q = ob + (size_t)px * FC + lg * 4;
            float4 v0, v1;
            v0.x = acc[tI][0][0] + bias0.x; v0.y = acc[tI][0][1] + bias0.y;
            v0.z = acc[tI][0][2] + bias0.z; v0.w = acc[tI][0][3] + bias0.w;
            v1.x = acc[tI][1][0] + bias1.x; v1.y = acc[tI][1][1] + bias1.y;
            v1.z = acc[tI][1][2] + bias1.z; v1.w = acc[tI][1][3] + bias1.w;
            *(float4*)(q)      = v0;
            *(float4*)(q + 16) = v1;
        }
    }
}

extern "C" void kernel_launch(void* const* d_in, const int* in_sizes, int n_in,
                              void* d_out, int out_size, void* d_ws, size_t ws_size,
                              hipStream_t stream)
{
    const float* x      = (const float*)d_in[0];
    const float* params = (const float*)d_in[1];
    float*       out    = (float*)d_out;

    if (ws_size >= WS_NEED && d_ws != nullptr) {
        bf16x8* ws = (bf16x8*)d_ws;
        hipLaunchKernelGGL(wprep, dim3(4, 32), dim3(256), 0, stream, params, ws);
        hipLaunchKernelGGL((conv3x3_mfma<true>), dim3(512), dim3(256), 0, stream,
                           x, params, out, (const bf16x8*)ws);
    } else {
        hipLaunchKernelGGL((conv3x3_mfma<false>), dim3(512), dim3(256), 0, stream,
                           x, params, out, (const bf16x8*)nullptr);
    }
}